// Round 16
// baseline (128.822 us; speedup 1.0000x reference)
//
#include <hip/hip_runtime.h>

typedef __attribute__((ext_vector_type(8))) short short8;
typedef __attribute__((ext_vector_type(4))) float f32x4;

// Problem constants (B, D, E, S, H, Z) = (16384, 512, 16, 1, 256, 256)
constexpr int Bsz = 16384;
constexpr int Dd  = 512;
constexpr int Ee  = 16;
constexpr int Hh  = 256;
constexpr int Zz  = 256;
constexpr int BT  = 64;       // b rows per block
constexpr int WCLD = 17;      // wc padded stride
constexpr int HLD  = 544;     // hidB row stride bytes (512 + 32 pad)
constexpr int CHK  = 16384;   // weight chunk: 256 rows x 32 k bf16 = 16KB
// LDS: hA 64KB | per-wave triple bufs 4x3x4KB | hidB 34KB | wc 4.25KB | b1 1KB
constexpr int OFF_P   = 65536;
constexpr int OFF_HID = OFF_P + 4 * 3 * 4096;        // 114688
constexpr int OFF_WC  = OFF_HID + BT * HLD;          // 149504
constexpr int OFF_B1  = OFF_WC + 64 * WCLD * 4;      // 153856
constexpr int SMEM_MAIN = OFF_B1 + 1024;             // 154880 B

// counted per-wave vmcnt wait; memory clobber orders following ds_reads
#define WAITV(N) asm volatile("s_waitcnt vmcnt(" #N ")" ::: "memory")

__device__ __forceinline__ unsigned short f2bf(float f) {
    unsigned u = __float_as_uint(f);
    u += 0x7FFFu + ((u >> 16) & 1u);          // round-to-nearest-even
    return (unsigned short)(u >> 16);
}

// hidB swizzled byte offset (R10/R11-validated)
__device__ __forceinline__ int hoff(int b, int h) {
    return b * HLD + ((((h) >> 3) ^ (b & 7)) << 4) + ((h & 7) << 1);
}

// packed-weight byte offset: chunk 16KB | row*64 | col XOR | k&7 (R11-validated)
__device__ __forceinline__ size_t woff(int row, int k) {
    return (size_t)(k >> 5) * CHK + (size_t)row * 64 +
           ((((k >> 3) & 3) ^ ((row >> 1) & 3)) << 4) + ((k & 7) << 1);
}

// stage this wave's private 4KB slice of a 16KB chunk (4 x 1KB loads)
__device__ __forceinline__ void stage4(const char* chunkBase, char* ldsbuf,
                                       int wv, int lane) {
    const char* g = chunkBase + wv * 4096 + lane * 16;
    #pragma unroll
    for (int r = 0; r < 4; ++r)
        __builtin_amdgcn_global_load_lds(
            (const __attribute__((address_space(1))) void*)(g + r * 1024),
            (__attribute__((address_space(3))) void*)(ldsbuf + r * 1024), 16, 0, 0);
}

// Transpose + fp32->bf16 + pack into the chunked/swizzled image
__global__ void transpose_pack(const float* __restrict__ src,
                               unsigned short* __restrict__ dst,
                               int R, int C) {
    __shared__ float tile[64][65];
    int tilesC = C >> 6, tilesR = R >> 6;
    int bid = blockIdx.x;
    int e  = bid / (tilesR * tilesC);
    int rm = bid % (tilesR * tilesC);
    int rt = rm / tilesC;
    int ct = rm % tilesC;
    int t  = threadIdx.x;
    int c  = t & 63;
    int r0 = t >> 6;
    const float* s = src + (size_t)e * R * C + (size_t)(rt * 64) * C + ct * 64;
    #pragma unroll
    for (int i = 0; i < 16; ++i) {
        int r = r0 + i * 4;
        tile[r][c] = s[(size_t)r * C + c];
    }
    __syncthreads();
    char* dbase = (char*)dst + (size_t)e * R * C * 2;
    #pragma unroll
    for (int i = 0; i < 16; ++i) {
        int r = r0 + i * 4;
        int row_g = ct * 64 + r;        // output row (C-dim)
        int k_g   = rt * 64 + c;        // k (R-dim)
        *reinterpret_cast<unsigned short*>(dbase + woff(row_g, k_g)) =
            f2bf(tile[c][r]);
    }
}

// Fused SoftMoE, transposed-GEMM form: hidT[h][b], outT[z][b].
// 256 blocks x 256 threads (4 waves), 1 block/CU. R11 structure + hA-resident
// registers: each wave reads all 16 chunks' h-fragments ONCE after gating
// (256 VGPR), so GEMM1 does zero hA LDS reads across all 16 experts.
__global__ __launch_bounds__(256, 1) void moe_fused(
    const float* __restrict__ hptr,            // [B][512] f32
    const float* __restrict__ phi,             // [512][16] f32
    const float* __restrict__ b1,              // [16][256] f32
    const float* __restrict__ b2,              // [16][256] f32
    const char* __restrict__ w1c,              // packed W1, 256KB/expert
    const char* __restrict__ w2c,              // packed W2, 128KB/expert
    float* __restrict__ out)                   // [B][256] f32
{
    extern __shared__ char smem[];
    char*  hA   = smem;                         // [64][512] bf16, XOR-swizzled
    char*  hidB = smem + OFF_HID;               // [64 b][256 h] bf16, swizzled
    float* wc   = (float*)(smem + OFF_WC);      // [64][17] softmax

    const int t    = threadIdx.x;
    const int lane = t & 63;
    const int wv   = t >> 6;          // wave 0..3: owns h/z rows [wv*64, +64)
    const int l15  = lane & 15;
    const int lg   = lane >> 4;       // 0..3
    const int b0   = blockIdx.x * BT;
    const int csb  = (l15 >> 1) & 3;  // weight col-swizzle base

    char* pw = smem + OFF_P + wv * 12288;       // this wave's 3 x 4KB buffers

    // prologue: stage expert-0 chunks 0,1 (land during h-staging + gating)
    stage4(w1c, pw, wv, lane);
    stage4(w1c + CHK, pw + 4096, wv, lane);

    // ---- stage h tile -> bf16 swizzled LDS ----
    {
        const f32x4* hsrc = reinterpret_cast<const f32x4*>(hptr + (size_t)b0 * Dd);
        #pragma unroll
        for (int i = 0; i < 32; ++i) {
            int idx = t + i * 256;
            int row = idx >> 7;
            int kc  = idx & 127;
            int k   = kc << 2;
            f32x4 v = hsrc[(size_t)row * 128 + kc];
            unsigned lo = (unsigned)f2bf(v.x) | ((unsigned)f2bf(v.y) << 16);
            unsigned hi = (unsigned)f2bf(v.z) | ((unsigned)f2bf(v.w) << 16);
            int byte = (row << 10) + (((k >> 3) ^ (row & 7)) << 4) + ((k & 7) << 1);
            *reinterpret_cast<uint2*>(hA + byte) = make_uint2(lo, hi);
        }
    }
    __syncthreads();

    // ---- gating via MFMA: 64x16 logits (waves redundant), wave 0 stores ----
    {
        f32x4 g[4];
        #pragma unroll
        for (int m = 0; m < 4; ++m) g[m] = (f32x4){0.f, 0.f, 0.f, 0.f};
        #pragma unroll
        for (int kc = 0; kc < 16; ++kc) {
            int kb = kc * 32 + lg * 8;
            short8 bfr;
            #pragma unroll
            for (int j = 0; j < 8; ++j)
                bfr[j] = (short)f2bf(phi[(size_t)(kb + j) * Ee + l15]);
            #pragma unroll
            for (int m = 0; m < 4; ++m) {
                int row = m * 16 + l15;
                short8 af = *reinterpret_cast<const short8*>(
                    hA + (row << 10) + (((kb >> 3) ^ (row & 7)) << 4));
                g[m] = __builtin_amdgcn_mfma_f32_16x16x32_bf16(af, bfr, g[m], 0, 0, 0);
            }
        }
        if (wv == 0) {
            #pragma unroll
            for (int m = 0; m < 4; ++m)
                #pragma unroll
                for (int j = 0; j < 4; ++j)
                    wc[(m * 16 + lg * 4 + j) * WCLD + l15] = g[m][j];
        }
    }
    __syncthreads();
    if (t < 64) {
        float w[16];
        float mx = -1e30f;
        #pragma unroll
        for (int e = 0; e < 16; ++e) { w[e] = wc[t * WCLD + e]; mx = fmaxf(mx, w[e]); }
        float s = 0.f;
        #pragma unroll
        for (int e = 0; e < 16; ++e) { w[e] = __expf(w[e] - mx); s += w[e]; }
        float inv = 1.f / s;
        #pragma unroll
        for (int e = 0; e < 16; ++e) wc[t * WCLD + e] = w[e] * inv;
    }
    __syncthreads();

    // ---- hA -> registers, once: all 16 chunks' B-fragments (256 VGPR) ----
    short8 bhr[16][4];
    #pragma unroll
    for (int ci = 0; ci < 16; ++ci) {
        int kg = ci * 32 + lg * 8;
        #pragma unroll
        for (int n = 0; n < 4; ++n) {
            int b = n * 16 + l15;
            bhr[ci][n] = *reinterpret_cast<const short8*>(
                hA + (b << 10) + (((kg >> 3) ^ (b & 7)) << 4));
        }
    }

    f32x4 outacc[4][4];
    #pragma unroll
    for (int mi = 0; mi < 4; ++mi)
        #pragma unroll
        for (int n = 0; n < 4; ++n) outacc[mi][n] = (f32x4){0.f, 0.f, 0.f, 0.f};

    const char* w1e = w1c;
    for (int e = 0; e < Ee; ++e) {
        const char* w2e = w2c + (size_t)e * (Hh * Hh * 2);
        const char* w1n = w1c + (size_t)((e + 1) & 15) * (Hh * Dd * 2);

        // b1 -> LDS (adds 1 to queue; folded into iter-0/1 waits)
        __builtin_amdgcn_global_load_lds(
            (const __attribute__((address_space(1))) void*)(b1 + (size_t)e * Hh + wv * 64 + lane),
            (__attribute__((address_space(3))) void*)(smem + OFF_B1 + wv * 256), 4, 0, 0);

        f32x4 hacc[4][4];
        #pragma unroll
        for (int mi = 0; mi < 4; ++mi)
            #pragma unroll
            for (int n = 0; n < 4; ++n) hacc[mi][n] = (f32x4){0.f, 0.f, 0.f, 0.f};

        // GEMM1-T: 16 chunks K=32, dist-2, wave-private, barrier-free.
        // bh comes from registers (bhr); only aw is read from LDS.
        // Ledger: iter0 [c0,c1,b1,c2]=13 wait 9; iter1 13 wait 9;
        //         iter2 [b1,c2,c3,c4]=13 wait 8 (b1 done); steady 12 wait 8.
        #pragma unroll
        for (int ci = 0; ci < 16; ++ci) {
            const char* nsrc = (ci + 2 < 16) ? (w1e + (ci + 2) * CHK)
                                             : (w2e + (ci - 14) * CHK);
            stage4(nsrc, pw + ((ci + 2) % 3) * 4096, wv, lane);
            if (ci < 2) { WAITV(9); } else { WAITV(8); }
            const char* pb = pw + (ci % 3) * 4096;
            short8 aw[4];
            #pragma unroll
            for (int mi = 0; mi < 4; ++mi) {
                int rp = mi * 16 + l15;
                aw[mi] = *reinterpret_cast<const short8*>(
                    pb + rp * 64 + ((lg ^ csb) << 4));
            }
            #pragma unroll
            for (int mi = 0; mi < 4; ++mi)
                #pragma unroll
                for (int n = 0; n < 4; ++n)
                    hacc[mi][n] = __builtin_amdgcn_mfma_f32_16x16x32_bf16(
                        aw[mi], bhr[ci][n], hacc[mi][n], 0, 0, 0);
        }

        // all waves done reading hidB (prev expert GEMM2) before overwriting
        asm volatile("s_barrier" ::: "memory");

        // epilogue1-T: v = relu(hid + b1)*c[b,e] -> bf16 hidB (b1 from LDS)
        {
            const float* b1w = (const float*)(smem + OFF_B1) + wv * 64;
            int hb0 = wv * 64 + lg * 4;
            #pragma unroll
            for (int mi = 0; mi < 4; ++mi) {
                int hb = hb0 + mi * 16;
                f32x4 b1v = *reinterpret_cast<const f32x4*>(b1w + lg * 4 + mi * 16);
                #pragma unroll
                for (int n = 0; n < 4; ++n) {
                    int b = n * 16 + l15;
                    float cbe = wc[b * WCLD + e];
                    float v0 = fmaxf(hacc[mi][n][0] + b1v[0], 0.f) * cbe;
                    float v1 = fmaxf(hacc[mi][n][1] + b1v[1], 0.f) * cbe;
                    float v2 = fmaxf(hacc[mi][n][2] + b1v[2], 0.f) * cbe;
                    float v3 = fmaxf(hacc[mi][n][3] + b1v[3], 0.f) * cbe;
                    unsigned lo = (unsigned)f2bf(v0) | ((unsigned)f2bf(v1) << 16);
                    unsigned hi = (unsigned)f2bf(v2) | ((unsigned)f2bf(v3) << 16);
                    *reinterpret_cast<uint2*>(hidB + hoff(b, hb)) = make_uint2(lo, hi);
                }
            }
        }
        asm volatile("s_waitcnt lgkmcnt(0)\n\ts_barrier" ::: "memory");

        // GEMM2-T: 8 chunks K=32 (g0,g1 prefetched during GEMM1 tail)
        #pragma unroll
        for (int gi = 0; gi < 8; ++gi) {
            const char* nsrc = (gi + 2 < 8) ? (w2e + (gi + 2) * CHK)
                                            : (w1n + (gi - 6) * CHK);
            stage4(nsrc, pw + (gi % 3) * 4096, wv, lane);   // (16+gi+2)%3 = gi%3
            WAITV(8);
            const char* pb = pw + ((gi + 1) % 3) * 4096;    // (16+gi)%3
            short8 aw[4], bh[4];
            #pragma unroll
            for (int mi = 0; mi < 4; ++mi) {
                int rp = mi * 16 + l15;
                aw[mi] = *reinterpret_cast<const short8*>(
                    pb + rp * 64 + ((lg ^ csb) << 4));
            }
            int kg = gi * 32 + lg * 8;
            #pragma unroll
            for (int n = 0; n < 4; ++n) {
                int b = n * 16 + l15;
                bh[n] = *reinterpret_cast<const short8*>(
                    hidB + b * HLD + (((kg >> 3) ^ (b & 7)) << 4));
            }
            #pragma unroll
            for (int mi = 0; mi < 4; ++mi)
                #pragma unroll
                for (int n = 0; n < 4; ++n)
                    outacc[mi][n] = __builtin_amdgcn_mfma_f32_16x16x32_bf16(
                        aw[mi], bh[n], outacc[mi][n], 0, 0, 0);
        }

        w1e = w1n;
    }

    // ---- final epilogue: out[b][z] = outT[z][b] + sum_e c[b,e]*b2[e,z] ----
    {
        int zb = wv * 64 + lg * 4;          // mi adds 16
        #pragma unroll
        for (int e = 0; e < 16; ++e) {
            float cbe[4];
            #pragma unroll
            for (int n = 0; n < 4; ++n) cbe[n] = wc[(n * 16 + l15) * WCLD + e];
            #pragma unroll
            for (int mi = 0; mi < 4; ++mi) {
                f32x4 b2v = *reinterpret_cast<const f32x4*>(
                    b2 + (size_t)e * Zz + zb + mi * 16);
                #pragma unroll
                for (int n = 0; n < 4; ++n) outacc[mi][n] += cbe[n] * b2v;
            }
        }
        #pragma unroll
        for (int mi = 0; mi < 4; ++mi) {
            #pragma unroll
            for (int n = 0; n < 4; ++n) {
                int b = b0 + n * 16 + l15;
                *reinterpret_cast<f32x4*>(out + (size_t)b * Zz + zb + mi * 16) =
                    outacc[mi][n];
            }
        }
    }
    // drain dangling wrap-around prefetches before wave exit
    asm volatile("s_waitcnt vmcnt(0)" ::: "memory");
}

extern "C" void kernel_launch(void* const* d_in, const int* in_sizes, int n_in,
                              void* d_out, int out_size, void* d_ws, size_t ws_size,
                              hipStream_t stream) {
    const float* h   = (const float*)d_in[0];
    const float* phi = (const float*)d_in[1];
    const float* W1  = (const float*)d_in[2];
    const float* b1  = (const float*)d_in[3];
    const float* W2  = (const float*)d_in[4];
    const float* b2  = (const float*)d_in[5];
    float* out = (float*)d_out;

    unsigned short* w1p = (unsigned short*)d_ws;                      // 4 MB packed
    unsigned short* w2p = w1p + (size_t)Ee * Hh * Dd;                 // 2 MB packed

    (void)hipFuncSetAttribute((const void*)moe_fused,
                              hipFuncAttributeMaxDynamicSharedMemorySize, SMEM_MAIN);

    transpose_pack<<<Ee * (Dd / 64) * (Hh / 64), 256, 0, stream>>>(W1, w1p, Dd, Hh);
    transpose_pack<<<Ee * (Hh / 64) * (Zz / 64), 256, 0, stream>>>(W2, w2p, Hh, Zz);

    moe_fused<<<Bsz / BT, 256, SMEM_MAIN, stream>>>(
        h, phi, b1, b2, (const char*)w1p, (const char*)w2p, out);
}

// Round 17
// 125.273 us; speedup vs baseline: 1.0283x; 1.0283x over previous
//
#include <hip/hip_runtime.h>

typedef __attribute__((ext_vector_type(8))) short short8;
typedef __attribute__((ext_vector_type(4))) float f32x4;

// Problem constants (B, D, E, S, H, Z) = (16384, 512, 16, 1, 256, 256)
constexpr int Bsz = 16384;
constexpr int Dd  = 512;
constexpr int Ee  = 16;
constexpr int Hh  = 256;
constexpr int Zz  = 256;
constexpr int BT  = 64;       // b rows per block
constexpr int WCLD = 17;      // wc padded stride
constexpr int HLD  = 544;     // hidB row stride bytes (512 + 32 pad)
constexpr int CHK  = 16384;   // weight chunk: 256 rows x 32 k bf16 = 16KB
// LDS: hA 64KB | per-wave triple bufs 4x3x4KB | hidB 34KB | wc 4.25KB | b1 1KB
constexpr int OFF_P   = 65536;
constexpr int OFF_HID = OFF_P + 4 * 3 * 4096;        // 114688
constexpr int OFF_WC  = OFF_HID + BT * HLD;          // 149504
constexpr int OFF_B1  = OFF_WC + 64 * WCLD * 4;      // 153856
constexpr int SMEM_MAIN = OFF_B1 + 1024;             // 154880 B

// counted per-wave vmcnt wait; memory clobber orders following ds_reads
#define WAITV(N) asm volatile("s_waitcnt vmcnt(" #N ")" ::: "memory")

__device__ __forceinline__ unsigned short f2bf(float f) {
    unsigned u = __float_as_uint(f);
    u += 0x7FFFu + ((u >> 16) & 1u);          // round-to-nearest-even
    return (unsigned short)(u >> 16);
}

// hidB swizzled byte offset (R10/R11-validated)
__device__ __forceinline__ int hoff(int b, int h) {
    return b * HLD + ((((h) >> 3) ^ (b & 7)) << 4) + ((h & 7) << 1);
}

// packed-weight byte offset: chunk 16KB | row*64 | col XOR | k&7 (R11-validated)
__device__ __forceinline__ size_t woff(int row, int k) {
    return (size_t)(k >> 5) * CHK + (size_t)row * 64 +
           ((((k >> 3) & 3) ^ ((row >> 1) & 3)) << 4) + ((k & 7) << 1);
}

// stage this wave's private 4KB slice of a 16KB chunk (4 x 1KB loads)
__device__ __forceinline__ void stage4(const char* chunkBase, char* ldsbuf,
                                       int wv, int lane) {
    const char* g = chunkBase + wv * 4096 + lane * 16;
    #pragma unroll
    for (int r = 0; r < 4; ++r)
        __builtin_amdgcn_global_load_lds(
            (const __attribute__((address_space(1))) void*)(g + r * 1024),
            (__attribute__((address_space(3))) void*)(ldsbuf + r * 1024), 16, 0, 0);
}

// Transpose + fp32->bf16 + pack into the chunked/swizzled image
__global__ void transpose_pack(const float* __restrict__ src,
                               unsigned short* __restrict__ dst,
                               int R, int C) {
    __shared__ float tile[64][65];
    int tilesC = C >> 6, tilesR = R >> 6;
    int bid = blockIdx.x;
    int e  = bid / (tilesR * tilesC);
    int rm = bid % (tilesR * tilesC);
    int rt = rm / tilesC;
    int ct = rm % tilesC;
    int t  = threadIdx.x;
    int c  = t & 63;
    int r0 = t >> 6;
    const float* s = src + (size_t)e * R * C + (size_t)(rt * 64) * C + ct * 64;
    #pragma unroll
    for (int i = 0; i < 16; ++i) {
        int r = r0 + i * 4;
        tile[r][c] = s[(size_t)r * C + c];
    }
    __syncthreads();
    char* dbase = (char*)dst + (size_t)e * R * C * 2;
    #pragma unroll
    for (int i = 0; i < 16; ++i) {
        int r = r0 + i * 4;
        int row_g = ct * 64 + r;        // output row (C-dim)
        int k_g   = rt * 64 + c;        // k (R-dim)
        *reinterpret_cast<unsigned short*>(dbase + woff(row_g, k_g)) =
            f2bf(tile[c][r]);
    }
}

// Fused SoftMoE, transposed-GEMM form: hidT[h][b], outT[z][b].
// 256 blocks x 256 threads (4 waves), 1 block/CU. Waves free-run through
// wave-private staged weight chunks (dist-2 counted vmcnt, NO barriers in the
// K loops); only 2 barriers/expert around the shared hidB tile.
__global__ __launch_bounds__(256, 1) void moe_fused(
    const float* __restrict__ hptr,            // [B][512] f32
    const float* __restrict__ phi,             // [512][16] f32
    const float* __restrict__ b1,              // [16][256] f32
    const float* __restrict__ b2,              // [16][256] f32
    const char* __restrict__ w1c,              // packed W1, 256KB/expert
    const char* __restrict__ w2c,              // packed W2, 128KB/expert
    float* __restrict__ out)                   // [B][256] f32
{
    extern __shared__ char smem[];
    char*  hA   = smem;                         // [64][512] bf16, XOR-swizzled
    char*  hidB = smem + OFF_HID;               // [64 b][256 h] bf16, swizzled
    float* wc   = (float*)(smem + OFF_WC);      // [64][17] softmax

    const int t    = threadIdx.x;
    const int lane = t & 63;
    const int wv   = t >> 6;          // wave 0..3: owns h/z rows [wv*64, +64)
    const int l15  = lane & 15;
    const int lg   = lane >> 4;       // 0..3
    const int b0   = blockIdx.x * BT;
    const int csb  = (l15 >> 1) & 3;  // weight col-swizzle base

    char* pw = smem + OFF_P + wv * 12288;       // this wave's 3 x 4KB buffers

    // prologue: stage expert-0 chunks 0,1 (land during h-staging + gating)
    stage4(w1c, pw, wv, lane);
    stage4(w1c + CHK, pw + 4096, wv, lane);

    // ---- stage h tile -> bf16 swizzled LDS ----
    {
        const f32x4* hsrc = reinterpret_cast<const f32x4*>(hptr + (size_t)b0 * Dd);
        #pragma unroll
        for (int i = 0; i < 32; ++i) {
            int idx = t + i * 256;
            int row = idx >> 7;
            int kc  = idx & 127;
            int k   = kc << 2;
            f32x4 v = hsrc[(size_t)row * 128 + kc];
            unsigned lo = (unsigned)f2bf(v.x) | ((unsigned)f2bf(v.y) << 16);
            unsigned hi = (unsigned)f2bf(v.z) | ((unsigned)f2bf(v.w) << 16);
            int byte = (row << 10) + (((k >> 3) ^ (row & 7)) << 4) + ((k & 7) << 1);
            *reinterpret_cast<uint2*>(hA + byte) = make_uint2(lo, hi);
        }
    }
    __syncthreads();

    // ---- gating via MFMA: 64x16 logits (waves redundant), wave 0 stores ----
    {
        f32x4 g[4];
        #pragma unroll
        for (int m = 0; m < 4; ++m) g[m] = (f32x4){0.f, 0.f, 0.f, 0.f};
        #pragma unroll
        for (int kc = 0; kc < 16; ++kc) {
            int kb = kc * 32 + lg * 8;
            short8 bfr;
            #pragma unroll
            for (int j = 0; j < 8; ++j)
                bfr[j] = (short)f2bf(phi[(size_t)(kb + j) * Ee + l15]);
            #pragma unroll
            for (int m = 0; m < 4; ++m) {
                int row = m * 16 + l15;
                short8 af = *reinterpret_cast<const short8*>(
                    hA + (row << 10) + (((kb >> 3) ^ (row & 7)) << 4));
                g[m] = __builtin_amdgcn_mfma_f32_16x16x32_bf16(af, bfr, g[m], 0, 0, 0);
            }
        }
        if (wv == 0) {
            #pragma unroll
            for (int m = 0; m < 4; ++m)
                #pragma unroll
                for (int j = 0; j < 4; ++j)
                    wc[(m * 16 + lg * 4 + j) * WCLD + l15] = g[m][j];
        }
    }
    __syncthreads();
    if (t < 64) {
        float w[16];
        float mx = -1e30f;
        #pragma unroll
        for (int e = 0; e < 16; ++e) { w[e] = wc[t * WCLD + e]; mx = fmaxf(mx, w[e]); }
        float s = 0.f;
        #pragma unroll
        for (int e = 0; e < 16; ++e) { w[e] = __expf(w[e] - mx); s += w[e]; }
        float inv = 1.f / s;
        #pragma unroll
        for (int e = 0; e < 16; ++e) wc[t * WCLD + e] = w[e] * inv;
    }
    __syncthreads();

    f32x4 outacc[4][4];
    #pragma unroll
    for (int mi = 0; mi < 4; ++mi)
        #pragma unroll
        for (int n = 0; n < 4; ++n) outacc[mi][n] = (f32x4){0.f, 0.f, 0.f, 0.f};

    const char* w1e = w1c;
    for (int e = 0; e < Ee; ++e) {
        const char* w2e = w2c + (size_t)e * (Hh * Hh * 2);
        const char* w1n = w1c + (size_t)((e + 1) & 15) * (Hh * Dd * 2);

        // b1 -> LDS (adds 1 to queue; folded into iter-0/1 waits)
        __builtin_amdgcn_global_load_lds(
            (const __attribute__((address_space(1))) void*)(b1 + (size_t)e * Hh + wv * 64 + lane),
            (__attribute__((address_space(3))) void*)(smem + OFF_B1 + wv * 256), 4, 0, 0);

        f32x4 hacc[4][4];
        #pragma unroll
        for (int mi = 0; mi < 4; ++mi)
            #pragma unroll
            for (int n = 0; n < 4; ++n) hacc[mi][n] = (f32x4){0.f, 0.f, 0.f, 0.f};

        // GEMM1-T: 16 chunks K=32, dist-2, wave-private, barrier-free.
        // Ledger: iter0 [c0,c1,b1,c2]=13 wait 9; iter1 13 wait 9;
        //         iter2 [b1,c2,c3,c4]=13 wait 8 (b1 done); steady 12 wait 8.
        #pragma unroll
        for (int ci = 0; ci < 16; ++ci) {
            const char* nsrc = (ci + 2 < 16) ? (w1e + (ci + 2) * CHK)
                                             : (w2e + (ci - 14) * CHK);
            stage4(nsrc, pw + ((ci + 2) % 3) * 4096, wv, lane);
            if (ci < 2) { WAITV(9); } else { WAITV(8); }
            const char* pb = pw + (ci % 3) * 4096;
            short8 aw[4], bh[4];
            #pragma unroll
            for (int mi = 0; mi < 4; ++mi) {
                int rp = mi * 16 + l15;
                aw[mi] = *reinterpret_cast<const short8*>(
                    pb + rp * 64 + ((lg ^ csb) << 4));
            }
            int kg = ci * 32 + lg * 8;
            #pragma unroll
            for (int n = 0; n < 4; ++n) {
                int b = n * 16 + l15;
                bh[n] = *reinterpret_cast<const short8*>(
                    hA + (b << 10) + (((kg >> 3) ^ (b & 7)) << 4));
            }
            #pragma unroll
            for (int mi = 0; mi < 4; ++mi)
                #pragma unroll
                for (int n = 0; n < 4; ++n)
                    hacc[mi][n] = __builtin_amdgcn_mfma_f32_16x16x32_bf16(
                        aw[mi], bh[n], hacc[mi][n], 0, 0, 0);
        }

        // all waves done reading hidB (prev expert GEMM2) before overwriting
        asm volatile("s_barrier" ::: "memory");

        // epilogue1-T: v = relu(hid + b1)*c[b,e] -> bf16 hidB (b1 from LDS)
        {
            const float* b1w = (const float*)(smem + OFF_B1) + wv * 64;
            int hb0 = wv * 64 + lg * 4;
            #pragma unroll
            for (int mi = 0; mi < 4; ++mi) {
                int hb = hb0 + mi * 16;
                f32x4 b1v = *reinterpret_cast<const f32x4*>(b1w + lg * 4 + mi * 16);
                #pragma unroll
                for (int n = 0; n < 4; ++n) {
                    int b = n * 16 + l15;
                    float cbe = wc[b * WCLD + e];
                    float v0 = fmaxf(hacc[mi][n][0] + b1v[0], 0.f) * cbe;
                    float v1 = fmaxf(hacc[mi][n][1] + b1v[1], 0.f) * cbe;
                    float v2 = fmaxf(hacc[mi][n][2] + b1v[2], 0.f) * cbe;
                    float v3 = fmaxf(hacc[mi][n][3] + b1v[3], 0.f) * cbe;
                    unsigned lo = (unsigned)f2bf(v0) | ((unsigned)f2bf(v1) << 16);
                    unsigned hi = (unsigned)f2bf(v2) | ((unsigned)f2bf(v3) << 16);
                    *reinterpret_cast<uint2*>(hidB + hoff(b, hb)) = make_uint2(lo, hi);
                }
            }
        }
        asm volatile("s_waitcnt lgkmcnt(0)\n\ts_barrier" ::: "memory");

        // GEMM2-T: 8 chunks K=32 (g0,g1 prefetched during GEMM1 tail)
        #pragma unroll
        for (int gi = 0; gi < 8; ++gi) {
            const char* nsrc = (gi + 2 < 8) ? (w2e + (gi + 2) * CHK)
                                            : (w1n + (gi - 6) * CHK);
            stage4(nsrc, pw + (gi % 3) * 4096, wv, lane);   // (16+gi+2)%3 = gi%3
            WAITV(8);
            const char* pb = pw + ((gi + 1) % 3) * 4096;    // (16+gi)%3
            short8 aw[4], bh[4];
            #pragma unroll
            for (int mi = 0; mi < 4; ++mi) {
                int rp = mi * 16 + l15;
                aw[mi] = *reinterpret_cast<const short8*>(
                    pb + rp * 64 + ((lg ^ csb) << 4));
            }
            int kg = gi * 32 + lg * 8;
            #pragma unroll
            for (int n = 0; n < 4; ++n) {
                int b = n * 16 + l15;
                bh[n] = *reinterpret_cast<const short8*>(
                    hidB + b * HLD + (((kg >> 3) ^ (b & 7)) << 4));
            }
            #pragma unroll
            for (int mi = 0; mi < 4; ++mi)
                #pragma unroll
                for (int n = 0; n < 4; ++n)
                    outacc[mi][n] = __builtin_amdgcn_mfma_f32_16x16x32_bf16(
                        aw[mi], bh[n], outacc[mi][n], 0, 0, 0);
        }

        w1e = w1n;
    }

    // ---- final epilogue: out[b][z] = outT[z][b] + sum_e c[b,e]*b2[e,z] ----
    {
        int zb = wv * 64 + lg * 4;          // mi adds 16
        #pragma unroll
        for (int e = 0; e < 16; ++e) {
            float cbe[4];
            #pragma unroll
            for (int n = 0; n < 4; ++n) cbe[n] = wc[(n * 16 + l15) * WCLD + e];
            #pragma unroll
            for (int mi = 0; mi < 4; ++mi) {
                f32x4 b2v = *reinterpret_cast<const f32x4*>(
                    b2 + (size_t)e * Zz + zb + mi * 16);
                #pragma unroll
                for (int n = 0; n < 4; ++n) outacc[mi][n] += cbe[n] * b2v;
            }
        }
        #pragma unroll
        for (int mi = 0; mi < 4; ++mi) {
            #pragma unroll
            for (int n = 0; n < 4; ++n) {
                int b = b0 + n * 16 + l15;
                *reinterpret_cast<f32x4*>(out + (size_t)b * Zz + zb + mi * 16) =
                    outacc[mi][n];
            }
        }
    }
    // drain dangling wrap-around prefetches before wave exit
    asm volatile("s_waitcnt vmcnt(0)" ::: "memory");
}

extern "C" void kernel_launch(void* const* d_in, const int* in_sizes, int n_in,
                              void* d_out, int out_size, void* d_ws, size_t ws_size,
                              hipStream_t stream) {
    const float* h   = (const float*)d_in[0];
    const float* phi = (const float*)d_in[1];
    const float* W1  = (const float*)d_in[2];
    const float* b1  = (const float*)d_in[3];
    const float* W2  = (const float*)d_in[4];
    const float* b2  = (const float*)d_in[5];
    float* out = (float*)d_out;

    unsigned short* w1p = (unsigned short*)d_ws;                      // 4 MB packed
    unsigned short* w2p = w1p + (size_t)Ee * Hh * Dd;                 // 2 MB packed

    (void)hipFuncSetAttribute((const void*)moe_fused,
                              hipFuncAttributeMaxDynamicSharedMemorySize, SMEM_MAIN);

    transpose_pack<<<Ee * (Dd / 64) * (Hh / 64), 256, 0, stream>>>(W1, w1p, Dd, Hh);
    transpose_pack<<<Ee * (Hh / 64) * (Zz / 64), 256, 0, stream>>>(W2, w2p, Hh, Zz);

    moe_fused<<<Bsz / BT, 256, SMEM_MAIN, stream>>>(
        h, phi, b1, b2, (const char*)w1p, (const char*)w2p, out);
}

// Round 18
// 119.904 us; speedup vs baseline: 1.0744x; 1.0448x over previous
//
#include <hip/hip_runtime.h>

typedef __attribute__((ext_vector_type(8))) short short8;
typedef __attribute__((ext_vector_type(4))) float f32x4;

// Problem constants (B, D, E, S, H, Z) = (16384, 512, 16, 1, 256, 256)
constexpr int Bsz = 16384;
constexpr int Dd  = 512;
constexpr int Ee  = 16;
constexpr int Hh  = 256;
constexpr int Zz  = 256;
constexpr int BT  = 64;       // b rows per block
constexpr int WCLD = 17;      // wc padded stride
constexpr int HLD  = 544;     // hidB row stride bytes (512 + 32 pad)
constexpr int CHK  = 16384;   // weight chunk: 256 rows x 32 k bf16 = 16KB
// LDS: hA 64KB | per-wave triple bufs 8x3x2KB | hidB 34KB | wc 4.25KB | b1 2KB
constexpr int OFF_P   = 65536;
constexpr int OFF_HID = OFF_P + 8 * 3 * 2048;        // 114688
constexpr int OFF_WC  = OFF_HID + BT * HLD;          // 149504
constexpr int OFF_B1  = OFF_WC + 64 * WCLD * 4;      // 153856
constexpr int SMEM_MAIN = OFF_B1 + 2048;             // 155904 B

// counted per-wave vmcnt wait; memory clobber orders following ds_reads
#define WAITV(N) asm volatile("s_waitcnt vmcnt(" #N ")" ::: "memory")

__device__ __forceinline__ unsigned short f2bf(float f) {
    unsigned u = __float_as_uint(f);
    u += 0x7FFFu + ((u >> 16) & 1u);          // round-to-nearest-even
    return (unsigned short)(u >> 16);
}

// hidB swizzled byte offset (R10/R11-validated)
__device__ __forceinline__ int hoff(int b, int h) {
    return b * HLD + ((((h) >> 3) ^ (b & 7)) << 4) + ((h & 7) << 1);
}

// packed-weight byte offset: chunk 16KB | row*64 | col XOR | k&7 (R11-validated)
__device__ __forceinline__ size_t woff(int row, int k) {
    return (size_t)(k >> 5) * CHK + (size_t)row * 64 +
           ((((k >> 3) & 3) ^ ((row >> 1) & 3)) << 4) + ((k & 7) << 1);
}

// stage this wave's private 2KB slice of a 16KB chunk (2 x 1KB loads)
__device__ __forceinline__ void stage2(const char* chunkBase, char* ldsbuf,
                                       int wv, int lane) {
    const char* g = chunkBase + wv * 2048 + lane * 16;
    #pragma unroll
    for (int r = 0; r < 2; ++r)
        __builtin_amdgcn_global_load_lds(
            (const __attribute__((address_space(1))) void*)(g + r * 1024),
            (__attribute__((address_space(3))) void*)(ldsbuf + r * 1024), 16, 0, 0);
}

// Transpose + fp32->bf16 + pack into the chunked/swizzled image
__global__ void transpose_pack(const float* __restrict__ src,
                               unsigned short* __restrict__ dst,
                               int R, int C) {
    __shared__ float tile[64][65];
    int tilesC = C >> 6, tilesR = R >> 6;
    int bid = blockIdx.x;
    int e  = bid / (tilesR * tilesC);
    int rm = bid % (tilesR * tilesC);
    int rt = rm / tilesC;
    int ct = rm % tilesC;
    int t  = threadIdx.x;
    int c  = t & 63;
    int r0 = t >> 6;
    const float* s = src + (size_t)e * R * C + (size_t)(rt * 64) * C + ct * 64;
    #pragma unroll
    for (int i = 0; i < 16; ++i) {
        int r = r0 + i * 4;
        tile[r][c] = s[(size_t)r * C + c];
    }
    __syncthreads();
    char* dbase = (char*)dst + (size_t)e * R * C * 2;
    #pragma unroll
    for (int i = 0; i < 16; ++i) {
        int r = r0 + i * 4;
        int row_g = ct * 64 + r;        // output row (C-dim)
        int k_g   = rt * 64 + c;        // k (R-dim)
        *reinterpret_cast<unsigned short*>(dbase + woff(row_g, k_g)) =
            f2bf(tile[c][r]);
    }
}

// Fused SoftMoE, transposed-GEMM form: hidT[h][b], outT[z][b].
// 256 blocks x 512 threads (8 waves, 2/SIMD), 1 block/CU. R11 skeleton:
// free-running wave-private staged chunks (dist-2 counted vmcnt, no K-loop
// barriers). 2 waves/SIMD so one wave's MFMA burst hides the other wave's
// ds_read phase (intra-wave serialization was the R11 residual).
__global__ __launch_bounds__(512, 2) void moe_fused(
    const float* __restrict__ hptr,            // [B][512] f32
    const float* __restrict__ phi,             // [512][16] f32
    const float* __restrict__ b1,              // [16][256] f32
    const float* __restrict__ b2,              // [16][256] f32
    const char* __restrict__ w1c,              // packed W1, 256KB/expert
    const char* __restrict__ w2c,              // packed W2, 128KB/expert
    float* __restrict__ out)                   // [B][256] f32
{
    extern __shared__ char smem[];
    char*  hA   = smem;                         // [64][512] bf16, XOR-swizzled
    char*  hidB = smem + OFF_HID;               // [64 b][256 h] bf16, swizzled
    float* wc   = (float*)(smem + OFF_WC);      // [64][17] softmax

    const int t    = threadIdx.x;
    const int lane = t & 63;
    const int wv   = t >> 6;          // wave 0..7: owns h/z rows [wv*32, +32)
    const int l15  = lane & 15;
    const int lg   = lane >> 4;       // 0..3
    const int b0   = blockIdx.x * BT;
    const int csb  = (l15 >> 1) & 3;  // weight col-swizzle base

    char* pw = smem + OFF_P + wv * 6144;        // this wave's 3 x 2KB buffers

    // prologue: stage expert-0 chunks 0,1 (land during h-staging + gating)
    stage2(w1c, pw, wv, lane);
    stage2(w1c + CHK, pw + 2048, wv, lane);

    // ---- stage h tile -> bf16 swizzled LDS ----
    {
        const f32x4* hsrc = reinterpret_cast<const f32x4*>(hptr + (size_t)b0 * Dd);
        #pragma unroll
        for (int i = 0; i < 16; ++i) {
            int idx = t + i * 512;
            int row = idx >> 7;
            int kc  = idx & 127;
            int k   = kc << 2;
            f32x4 v = hsrc[(size_t)row * 128 + kc];
            unsigned lo = (unsigned)f2bf(v.x) | ((unsigned)f2bf(v.y) << 16);
            unsigned hi = (unsigned)f2bf(v.z) | ((unsigned)f2bf(v.w) << 16);
            int byte = (row << 10) + (((k >> 3) ^ (row & 7)) << 4) + ((k & 7) << 1);
            *reinterpret_cast<uint2*>(hA + byte) = make_uint2(lo, hi);
        }
    }
    __syncthreads();

    // ---- gating via MFMA: 64x16 logits (waves redundant), wave 0 stores ----
    {
        f32x4 g[4];
        #pragma unroll
        for (int m = 0; m < 4; ++m) g[m] = (f32x4){0.f, 0.f, 0.f, 0.f};
        #pragma unroll
        for (int kc = 0; kc < 16; ++kc) {
            int kb = kc * 32 + lg * 8;
            short8 bfr;
            #pragma unroll
            for (int j = 0; j < 8; ++j)
                bfr[j] = (short)f2bf(phi[(size_t)(kb + j) * Ee + l15]);
            #pragma unroll
            for (int m = 0; m < 4; ++m) {
                int row = m * 16 + l15;
                short8 af = *reinterpret_cast<const short8*>(
                    hA + (row << 10) + (((kb >> 3) ^ (row & 7)) << 4));
                g[m] = __builtin_amdgcn_mfma_f32_16x16x32_bf16(af, bfr, g[m], 0, 0, 0);
            }
        }
        if (wv == 0) {
            #pragma unroll
            for (int m = 0; m < 4; ++m)
                #pragma unroll
                for (int j = 0; j < 4; ++j)
                    wc[(m * 16 + lg * 4 + j) * WCLD + l15] = g[m][j];
        }
    }
    __syncthreads();
    if (t < 64) {
        float w[16];
        float mx = -1e30f;
        #pragma unroll
        for (int e = 0; e < 16; ++e) { w[e] = wc[t * WCLD + e]; mx = fmaxf(mx, w[e]); }
        float s = 0.f;
        #pragma unroll
        for (int e = 0; e < 16; ++e) { w[e] = __expf(w[e] - mx); s += w[e]; }
        float inv = 1.f / s;
        #pragma unroll
        for (int e = 0; e < 16; ++e) wc[t * WCLD + e] = w[e] * inv;
    }
    __syncthreads();

    f32x4 outacc[2][4];
    #pragma unroll
    for (int mi = 0; mi < 2; ++mi)
        #pragma unroll
        for (int n = 0; n < 4; ++n) outacc[mi][n] = (f32x4){0.f, 0.f, 0.f, 0.f};

    const char* w1e = w1c;
    for (int e = 0; e < Ee; ++e) {
        const char* w2e = w2c + (size_t)e * (Hh * Hh * 2);
        const char* w1n = w1c + (size_t)((e + 1) & 15) * (Hh * Dd * 2);

        // b1 -> LDS: wave w loads b1[e][w*32 + (lane&31)] (dup lanes 32-63)
        __builtin_amdgcn_global_load_lds(
            (const __attribute__((address_space(1))) void*)(b1 + (size_t)e * Hh + wv * 32 + (lane & 31)),
            (__attribute__((address_space(3))) void*)(smem + OFF_B1 + wv * 256), 4, 0, 0);

        f32x4 hacc[2][4];
        #pragma unroll
        for (int mi = 0; mi < 2; ++mi)
            #pragma unroll
            for (int n = 0; n < 4; ++n) hacc[mi][n] = (f32x4){0.f, 0.f, 0.f, 0.f};

        // GEMM1-T: 16 chunks K=32, dist-2, wave-private, barrier-free.
        // Ledger (2 loads/chunk): iter0 [c0,c1,b1,c2]=7 wait 5; iter1 7 wait 5;
        //         iter2 [b1,c2,c3,c4]=7 wait 4 (b1 done); steady 6 wait 4.
        #pragma unroll
        for (int ci = 0; ci < 16; ++ci) {
            const char* nsrc = (ci + 2 < 16) ? (w1e + (ci + 2) * CHK)
                                             : (w2e + (ci - 14) * CHK);
            stage2(nsrc, pw + ((ci + 2) % 3) * 2048, wv, lane);
            if (ci < 2) { WAITV(5); } else { WAITV(4); }
            const char* pb = pw + (ci % 3) * 2048;
            short8 aw[2], bh[4];
            #pragma unroll
            for (int mi = 0; mi < 2; ++mi) {
                int rp = mi * 16 + l15;
                aw[mi] = *reinterpret_cast<const short8*>(
                    pb + rp * 64 + ((lg ^ csb) << 4));
            }
            int kg = ci * 32 + lg * 8;
            #pragma unroll
            for (int n = 0; n < 4; ++n) {
                int b = n * 16 + l15;
                bh[n] = *reinterpret_cast<const short8*>(
                    hA + (b << 10) + (((kg >> 3) ^ (b & 7)) << 4));
            }
            #pragma unroll
            for (int mi = 0; mi < 2; ++mi)
                #pragma unroll
                for (int n = 0; n < 4; ++n)
                    hacc[mi][n] = __builtin_amdgcn_mfma_f32_16x16x32_bf16(
                        aw[mi], bh[n], hacc[mi][n], 0, 0, 0);
        }

        // all waves done reading hidB (prev expert GEMM2) before overwriting
        asm volatile("s_barrier" ::: "memory");

        // epilogue1-T: v = relu(hid + b1)*c[b,e] -> bf16 hidB (b1 from LDS)
        {
            const float* b1w = (const float*)(smem + OFF_B1 + wv * 256);
            int hb0 = wv * 32 + lg * 4;
            #pragma unroll
            for (int mi = 0; mi < 2; ++mi) {
                int hb = hb0 + mi * 16;
                f32x4 b1v = *reinterpret_cast<const f32x4*>(b1w + lg * 4 + mi * 16);
                #pragma unroll
                for (int n = 0; n < 4; ++n) {
                    int b = n * 16 + l15;
                    float cbe = wc[b * WCLD + e];
                    float v0 = fmaxf(hacc[mi][n][0] + b1v[0], 0.f) * cbe;
                    float v1 = fmaxf(hacc[mi][n][1] + b1v[1], 0.f) * cbe;
                    float v2 = fmaxf(hacc[mi][n][2] + b1v[2], 0.f) * cbe;
                    float v3 = fmaxf(hacc[mi][n][3] + b1v[3], 0.f) * cbe;
                    unsigned lo = (unsigned)f2bf(v0) | ((unsigned)f2bf(v1) << 16);
                    unsigned hi = (unsigned)f2bf(v2) | ((unsigned)f2bf(v3) << 16);
                    *reinterpret_cast<uint2*>(hidB + hoff(b, hb)) = make_uint2(lo, hi);
                }
            }
        }
        asm volatile("s_waitcnt lgkmcnt(0)\n\ts_barrier" ::: "memory");

        // GEMM2-T: 8 chunks K=32 (g0,g1 prefetched during GEMM1 tail)
        #pragma unroll
        for (int gi = 0; gi < 8; ++gi) {
            const char* nsrc = (gi + 2 < 8) ? (w2e + (gi + 2) * CHK)
                                            : (w1n + (gi - 6) * CHK);
            stage2(nsrc, pw + (gi % 3) * 2048, wv, lane);   // (16+gi+2)%3 = gi%3
            WAITV(4);
            const char* pb = pw + ((gi + 1) % 3) * 2048;    // (16+gi)%3
            short8 aw[2], bh[4];
            #pragma unroll
            for (int mi = 0; mi < 2; ++mi) {
                int rp = mi * 16 + l15;
                aw[mi] = *reinterpret_cast<const short8*>(
                    pb + rp * 64 + ((lg ^ csb) << 4));
            }
            int kg = gi * 32 + lg * 8;
            #pragma unroll
            for (int n = 0; n < 4; ++n) {
                int b = n * 16 + l15;
                bh[n] = *reinterpret_cast<const short8*>(
                    hidB + b * HLD + (((kg >> 3) ^ (b & 7)) << 4));
            }
            #pragma unroll
            for (int mi = 0; mi < 2; ++mi)
                #pragma unroll
                for (int n = 0; n < 4; ++n)
                    outacc[mi][n] = __builtin_amdgcn_mfma_f32_16x16x32_bf16(
                        aw[mi], bh[n], outacc[mi][n], 0, 0, 0);
        }

        w1e = w1n;
    }

    // ---- final epilogue: out[b][z] = outT[z][b] + sum_e c[b,e]*b2[e,z] ----
    {
        int zb = wv * 32 + lg * 4;          // mi adds 16
        #pragma unroll
        for (int e = 0; e < 16; ++e) {
            float cbe[4];
            #pragma unroll
            for (int n = 0; n < 4; ++n) cbe[n] = wc[(n * 16 + l15) * WCLD + e];
            #pragma unroll
            for (int mi = 0; mi < 2; ++mi) {
                f32x4 b2v = *reinterpret_cast<const f32x4*>(
                    b2 + (size_t)e * Zz + zb + mi * 16);
                #pragma unroll
                for (int n = 0; n < 4; ++n) outacc[mi][n] += cbe[n] * b2v;
            }
        }
        #pragma unroll
        for (int mi = 0; mi < 2; ++mi) {
            #pragma unroll
            for (int n = 0; n < 4; ++n) {
                int b = b0 + n * 16 + l15;
                *reinterpret_cast<f32x4*>(out + (size_t)b * Zz + zb + mi * 16) =
                    outacc[mi][n];
            }
        }
    }
    // drain dangling wrap-around prefetches before wave exit
    asm volatile("s_waitcnt vmcnt(0)" ::: "memory");
}

extern "C" void kernel_launch(void* const* d_in, const int* in_sizes, int n_in,
                              void* d_out, int out_size, void* d_ws, size_t ws_size,
                              hipStream_t stream) {
    const float* h   = (const float*)d_in[0];
    const float* phi = (const float*)d_in[1];
    const float* W1  = (const float*)d_in[2];
    const float* b1  = (const float*)d_in[3];
    const float* W2  = (const float*)d_in[4];
    const float* b2  = (const float*)d_in[5];
    float* out = (float*)d_out;

    unsigned short* w1p = (unsigned short*)d_ws;                      // 4 MB packed
    unsigned short* w2p = w1p + (size_t)Ee * Hh * Dd;                 // 2 MB packed

    (void)hipFuncSetAttribute((const void*)moe_fused,
                              hipFuncAttributeMaxDynamicSharedMemorySize, SMEM_MAIN);

    transpose_pack<<<Ee * (Dd / 64) * (Hh / 64), 256, 0, stream>>>(W1, w1p, Dd, Hh);
    transpose_pack<<<Ee * (Hh / 64) * (Zz / 64), 256, 0, stream>>>(W2, w2p, Hh, Zz);

    moe_fused<<<Bsz / BT, 512, SMEM_MAIN, stream>>>(
        h, phi, b1, b2, (const char*)w1p, (const char*)w2p, out);
}